// Round 10
// baseline (198.512 us; speedup 1.0000x reference)
//
#include <hip/hip_runtime.h>

typedef __attribute__((ext_vector_type(8))) short short8;
typedef __attribute__((ext_vector_type(4))) float f32x4;
typedef __attribute__((ext_vector_type(4))) float float4v;
typedef __attribute__((ext_vector_type(4))) unsigned short ushort4v;
typedef unsigned int __attribute__((may_alias)) u32ma;

#define B_   4
#define LQ   4096
#define LKV  4096
#define E_   1024
#define H_   128
#define NSPLIT 4
#define KVSPL (LKV / NSPLIT)   // 1024
#define NT    (KVSPL / 64)     // 16
#define WELEM (H_ * E_)        // 131072 elements per weight matrix

static __device__ __forceinline__ unsigned short bf16_rne(float f) {
    unsigned int u = __float_as_uint(f);
    u += 0x7fffu + ((u >> 16) & 1u);
    return (unsigned short)(u >> 16);
}
static __device__ __forceinline__ float bf16_tof(unsigned short h) {
    return __uint_as_float(((unsigned int)h) << 16);
}
static __device__ __forceinline__ f32x4 mfma16(short8 a, short8 b, f32x4 c) {
    return __builtin_amdgcn_mfma_f32_16x16x32_bf16(a, b, c, 0, 0, 0);
}
static __device__ __forceinline__ void gload16(const unsigned short* g, unsigned short* l) {
    __builtin_amdgcn_global_load_lds(
        (const __attribute__((address_space(1))) unsigned int*)g,
        (__attribute__((address_space(3))) unsigned int*)l, 16, 0, 0);
}

// ---------------------------------------------------------------------------
// One-time W conversion. NEW: block (0,0) also zeroes the 128 split-group
// counters used by attn's fused combine (stream order guarantees visibility).
// ---------------------------------------------------------------------------
__global__ __launch_bounds__(256) void convert_w_kernel(
    const float* __restrict__ Wq, const float* __restrict__ Wk, const float* __restrict__ Wv,
    unsigned short* __restrict__ wqh, unsigned short* __restrict__ wql,
    unsigned short* __restrict__ wkh, unsigned short* __restrict__ wkl,
    unsigned short* __restrict__ wvh, unsigned int* __restrict__ cnt)
{
    const int kb = blockIdx.x;       // 0..15
    const int which = blockIdx.y;    // 0:Wq 1:Wk 2:Wv
    const float* W = (which == 0) ? Wq : (which == 1) ? Wk : Wv;
    unsigned short* outh = (which == 0) ? wqh : (which == 1) ? wkh : wvh;
    unsigned short* outl = (which == 0) ? wql : wkl;
    const int t = threadIdx.x;
    if (kb == 0 && which == 0 && t < 128) cnt[t] = 0u;   // reset per launch
#pragma unroll
    for (int i = 0; i < 4; ++i) {
        const int c = t * 4 + i;                 // chunk 0..1023
        const int h = c >> 3;
        const int k = kb * 64 + (((c & 7) ^ (h & 7)) * 8);
        const float* src = W + (size_t)h * E_ + k;
        float4v v0 = *(const float4v*)(src);
        float4v v1 = *(const float4v*)(src + 4);
        short8 hi, lo;
#pragma unroll
        for (int e = 0; e < 4; ++e) {
            unsigned short h0 = bf16_rne(v0[e]);
            unsigned short h1 = bf16_rne(v1[e]);
            hi[e] = (short)h0; hi[e + 4] = (short)h1;
            lo[e] = (short)bf16_rne(v0[e] - bf16_tof(h0));
            lo[e + 4] = (short)bf16_rne(v1[e] - bf16_tof(h1));
        }
        *(short8*)&outh[(size_t)kb * 8192 + (size_t)c * 8] = hi;
        if (which < 2) *(short8*)&outl[(size_t)kb * 8192 + (size_t)c * 8] = lo;
    }
}

// ---------------------------------------------------------------------------
// Projection GEMM R7 (verified best; unchanged).
// ---------------------------------------------------------------------------
__global__ __launch_bounds__(512, 1) void proj_kernel(
    const float* __restrict__ x, const float* __restrict__ z,
    const unsigned short* __restrict__ wqh, const unsigned short* __restrict__ wql,
    const unsigned short* __restrict__ wkh, const unsigned short* __restrict__ wkl,
    const unsigned short* __restrict__ wvh,
    unsigned short* __restrict__ qhi, unsigned short* __restrict__ qlo,
    unsigned short* __restrict__ khi, unsigned short* __restrict__ klo,
    unsigned short* __restrict__ vt)
{
    const int bid = blockIdx.x;
    const bool qmode = bid < 128;
    const int m0 = (qmode ? bid : bid - 128) * 128;
    const float* Asrc = qmode ? x : z;
    const unsigned short* W1h = qmode ? wqh : wkh;
    const unsigned short* W1l = qmode ? wql : wkl;

    const int t = threadIdx.x;
    const int w = t >> 6, l = t & 63, lg = (l >> 4) & 3, ll = l & 15;
    const int mw = w & 3, nw = w >> 2;

    __shared__ unsigned short Ah[2][8192];     // 32 KiB [128 r][64 k] swizzled, dbuf
    __shared__ unsigned short Al[2][8192];     // 32 KiB
    __shared__ unsigned short Wh[2][8192];     // 32 KiB [128 h][64 k] swizzled, dbuf
    __shared__ unsigned short Wl[2][8192];     // 32 KiB
    __shared__ unsigned short Wv2[8192];       // 16 KiB single (kv-mode only)

    const int ar = t >> 2, aq = t & 3;
    float4v ra[4];
    auto loadA = [&](int e0) {
        const float* p = Asrc + (size_t)(m0 + ar) * E_ + e0 + aq * 16;
#pragma unroll
        for (int i = 0; i < 4; ++i) ra[i] = *(const float4v*)(p + i * 4);
    };
    auto writeA = [&](int ab) {
#pragma unroll
        for (int half = 0; half < 2; ++half) {
            short8 hi, lo;
#pragma unroll
            for (int e = 0; e < 4; ++e) {
                float v0 = ra[2 * half][e];
                float v1 = ra[2 * half + 1][e];
                unsigned short h0 = bf16_rne(v0);
                unsigned short h1 = bf16_rne(v1);
                hi[e] = (short)h0; hi[e + 4] = (short)h1;
                lo[e] = (short)bf16_rne(v0 - bf16_tof(h0));
                lo[e + 4] = (short)bf16_rne(v1 - bf16_tof(h1));
            }
            const int j = 2 * aq + half;
            const int off = ar * 64 + ((j ^ (ar & 7)) * 8);
            *(short8*)&Ah[ab][off] = hi;
            *(short8*)&Al[ab][off] = lo;
        }
    };
    auto issueW = [&](int kb, int bsel) {
#pragma unroll
        for (int i = 0; i < 2; ++i) {
            const int cbase = w * 128 + i * 64;
            const size_t so = (size_t)kb * 8192 + (size_t)(cbase + l) * 8;
            gload16(W1h + so, &Wh[bsel][(size_t)cbase * 8]);
            gload16(W1l + so, &Wl[bsel][(size_t)cbase * 8]);
        }
    };
    auto issueWv = [&](int kb) {
#pragma unroll
        for (int i = 0; i < 2; ++i) {
            const int cbase = w * 128 + i * 64;
            const size_t so = (size_t)kb * 8192 + (size_t)(cbase + l) * 8;
            gload16(wvh + so, &Wv2[(size_t)cbase * 8]);
        }
    };

    f32x4 acc[2][4], accv[2][4];
    const f32x4 zz = {0.f, 0.f, 0.f, 0.f};
#pragma unroll
    for (int rf = 0; rf < 2; ++rf)
#pragma unroll
        for (int cf = 0; cf < 4; ++cf) { acc[rf][cf] = zz; accv[rf][cf] = zz; }

    loadA(0);
    issueW(0, 0);
    if (!qmode) issueWv(0);
    asm volatile("s_waitcnt vmcnt(0)" ::: "memory");
    writeA(0);
    asm volatile("s_waitcnt lgkmcnt(0)" ::: "memory");
    __builtin_amdgcn_s_barrier();

    for (int kb = 0; kb < 16; ++kb) {
        const int cur = kb & 1;
        if (kb < 15) {
            loadA((kb + 1) * 64);
            issueW(kb + 1, cur ^ 1);
        }

#pragma unroll
        for (int ks = 0; ks < 2; ++ks) {
            short8 a_h[2], a_l[2];
#pragma unroll
            for (int rf = 0; rf < 2; ++rf) {
                const int r = mw * 32 + rf * 16 + ll;
                const int off = r * 64 + (((ks * 4 + lg) ^ (ll & 7)) * 8);
                a_h[rf] = *(const short8*)&Ah[cur][off];
                a_l[rf] = *(const short8*)&Al[cur][off];
            }
#pragma unroll
            for (int cf = 0; cf < 4; ++cf) {
                const int hrow = nw * 64 + cf * 16 + ll;
                const int off = hrow * 64 + (((ks * 4 + lg) ^ (ll & 7)) * 8);
                short8 bh = *(const short8*)&Wh[cur][off];
                short8 bl = *(const short8*)&Wl[cur][off];
#pragma unroll
                for (int rf = 0; rf < 2; ++rf) {
                    acc[rf][cf] = mfma16(a_h[rf], bh, acc[rf][cf]);
                    acc[rf][cf] = mfma16(a_h[rf], bl, acc[rf][cf]);
                    acc[rf][cf] = mfma16(a_l[rf], bh, acc[rf][cf]);
                }
                if (!qmode) {
                    short8 bv = *(const short8*)&Wv2[off];
#pragma unroll
                    for (int rf = 0; rf < 2; ++rf)
                        accv[rf][cf] = mfma16(a_h[rf], bv, accv[rf][cf]);
                }
            }
        }

        if (kb < 15) {
            writeA(cur ^ 1);
            if (!qmode) issueWv(kb + 1);
            asm volatile("s_waitcnt vmcnt(0) lgkmcnt(0)" ::: "memory");
            __builtin_amdgcn_sched_barrier(0);
            __builtin_amdgcn_s_barrier();
        }
    }

#pragma unroll
    for (int rf = 0; rf < 2; ++rf)
#pragma unroll
        for (int cf = 0; cf < 4; ++cf)
#pragma unroll
            for (int j = 0; j < 4; ++j) {
                const int m = m0 + mw * 32 + rf * 16 + 4 * lg + j;
                const int h = nw * 64 + cf * 16 + ll;
                const float val = acc[rf][cf][j];
                unsigned short hi = bf16_rne(val);
                unsigned short lo = bf16_rne(val - bf16_tof(hi));
                const size_t o = (size_t)m * H_ + h;
                if (qmode) {
                    qhi[o] = hi; qlo[o] = lo;
                } else {
                    khi[o] = hi; klo[o] = lo;
                    const int b = m >> 12, kv = m & 4095;
                    vt[(size_t)b * ((size_t)H_ * LKV) + (size_t)h * LKV + kv] =
                        bf16_rne(accv[rf][cf][j]);
                }
            }
}

// ---------------------------------------------------------------------------
// Flash attention R10 = R3 main loop (verified best) + FUSED COMBINE:
// last split-block per (bb,qt) group performs the 4-way combine in its
// epilogue (rocPRIM-style: stores -> threadfence (release) -> atomicAdd;
// winner: threadfence (acquire) -> read partials -> write out). Numerics
// identical to the old combine_kernel (same formula, same order).
// ---------------------------------------------------------------------------
__global__ __launch_bounds__(256, 2) void attn_kernel(
    const unsigned short* __restrict__ qhi, const unsigned short* __restrict__ qlo,
    const unsigned short* __restrict__ khi, const unsigned short* __restrict__ klo,
    const unsigned short* __restrict__ vt,
    float* __restrict__ Opart, float* __restrict__ msb, float* __restrict__ lsb,
    float* __restrict__ out, unsigned int* __restrict__ cnt)
{
    const int blk = blockIdx.x;         // 512 blocks
    const int bb = blk & 3;
    const int qt = (blk >> 2) & 31;
    const int split = blk >> 7;
    const int t = threadIdx.x;          // 0..255
    const int w = t >> 6, l = t & 63, lg = (l >> 4) & 3, ll = l & 15;

    __shared__ unsigned short Kh[8192];        // 16 KiB [64 kv][128 h] swizzled
    __shared__ unsigned short Kl[8192];        // 16 KiB
    __shared__ unsigned short Vb[8192];        // 16 KiB [128 h][64 kv] swizzled
    __shared__ unsigned short Pl[4][32][64];   // 16 KiB per-wave P staging
    __shared__ unsigned int sflag;

    const float CSC = 11.313708498984761f * 1.4426950408889634f;

    short8 qh[2][4], ql[2][4];
#pragma unroll
    for (int b = 0; b < 2; ++b) {
        const size_t qrow = (size_t)(bb * LQ + qt * 128 + w * 32 + b * 16 + ll) * H_;
#pragma unroll
        for (int ks = 0; ks < 4; ++ks) {
            qh[b][ks] = *(const short8*)(qhi + qrow + ks * 32 + lg * 8);
            ql[b][ks] = *(const short8*)(qlo + qrow + ks * 32 + lg * 8);
        }
    }

    const int kv_base = split * KVSPL;
    const unsigned short* khb = khi + (size_t)bb * LKV * H_;
    const unsigned short* klb = klo + (size_t)bb * LKV * H_;
    const unsigned short* vbg = vt + (size_t)bb * ((size_t)H_ * LKV);

    auto issue_K = [&](int kv0) {     // 8 loads/wave
#pragma unroll
        for (int ci = 0; ci < 4; ++ci) {
            const int chunk = w * 4 + ci;              // 0..15
            const int row = chunk * 4 + (l >> 4);      // kv row 0..63
            const int c = l & 15;                      // col-chunk
            const size_t so = (size_t)(kv0 + row) * H_ + ((c ^ (row & 7)) * 8);
            gload16(khb + so, &Kh[chunk * 512]);
            gload16(klb + so, &Kl[chunk * 512]);
        }
    };
    auto issue_V = [&](int kv0) {     // 4 loads/wave
#pragma unroll
        for (int ci = 0; ci < 4; ++ci) {
            const int chunk = w * 4 + ci;              // 0..15
            const int row = chunk * 8 + (l >> 3);      // h row 0..127
            const int c = l & 7;                       // col-chunk
            gload16(vbg + (size_t)row * LKV + kv0 + ((c ^ (row & 7)) * 8),
                    &Vb[chunk * 512]);
        }
    };

    f32x4 O[8][2];
    const f32x4 zz = {0.f, 0.f, 0.f, 0.f};
#pragma unroll
    for (int f = 0; f < 8; ++f) { O[f][0] = zz; O[f][1] = zz; }
    float mold[2] = {-1e30f, -1e30f};
    float lsum[2] = {0.f, 0.f};

    issue_K(kv_base);
    issue_V(kv_base);
    asm volatile("s_waitcnt vmcnt(0)" ::: "memory");
    __builtin_amdgcn_s_barrier();

    for (int ti = 0; ti < NT; ++ti) {
        // ---- QK^T (reads Kh/Kl; K(ti) drained at barrier#3 of ti-1) ----
        f32x4 S[4][2];
#pragma unroll
        for (int a = 0; a < 4; ++a) { S[a][0] = zz; S[a][1] = zz; }
        __builtin_amdgcn_s_setprio(1);
#pragma unroll
        for (int ks = 0; ks < 4; ++ks) {
#pragma unroll
            for (int a = 0; a < 4; ++a) {
                const int row = a * 16 + ll;
                const int off = row * 128 + (((ks * 4 + lg) ^ (ll & 7)) * 8);
                short8 kh  = *(const short8*)&Kh[off];
                short8 kl2 = *(const short8*)&Kl[off];
                S[a][0] = mfma16(kh,  qh[0][ks], S[a][0]);
                S[a][0] = mfma16(kh,  ql[0][ks], S[a][0]);
                S[a][0] = mfma16(kl2, qh[0][ks], S[a][0]);
                S[a][1] = mfma16(kh,  qh[1][ks], S[a][1]);
                S[a][1] = mfma16(kh,  ql[1][ks], S[a][1]);
                S[a][1] = mfma16(kl2, qh[1][ks], S[a][1]);
            }
        }
        __builtin_amdgcn_s_setprio(0);

        // ---- online softmax (per-wave; writes Pl[w]) ----
        float crr[2];
#pragma unroll
        for (int b = 0; b < 2; ++b) {
            float mx = S[0][b][0];
#pragma unroll
            for (int a = 0; a < 4; ++a)
#pragma unroll
                for (int j = 0; j < 4; ++j) mx = fmaxf(mx, S[a][b][j]);
            mx = fmaxf(mx, __shfl_xor(mx, 16));
            mx = fmaxf(mx, __shfl_xor(mx, 32));
            float mn = fmaxf(mold[b], mx * CSC);
            float corr = exp2f(mold[b] - mn);
            float ps = 0.f;
#pragma unroll
            for (int a = 0; a < 4; ++a) {
                float p0 = exp2f(fmaf(S[a][b][0], CSC, -mn));
                float p1 = exp2f(fmaf(S[a][b][1], CSC, -mn));
                float p2 = exp2f(fmaf(S[a][b][2], CSC, -mn));
                float p3 = exp2f(fmaf(S[a][b][3], CSC, -mn));
                ps += (p0 + p1) + (p2 + p3);
                unsigned int pk0, pk1;
                asm("v_cvt_pk_bf16_f32 %0, %1, %2" : "=v"(pk0) : "v"(p0), "v"(p1));
                asm("v_cvt_pk_bf16_f32 %0, %1, %2" : "=v"(pk1) : "v"(p2), "v"(p3));
                const int row = b * 16 + ll;
                u32ma* pd = (u32ma*)&Pl[w][0][0];
                const int di = row * 32 + (((2 * a + (lg >> 1)) ^ (ll & 7)) * 4) + 2 * (lg & 1);
                pd[di] = pk0;
                pd[di + 1] = pk1;
            }
            ps += __shfl_xor(ps, 16);
            ps += __shfl_xor(ps, 32);
            lsum[b] = lsum[b] * corr + ps;
            mold[b] = mn;
            crr[b] = corr;
        }
#pragma unroll
        for (int f = 0; f < 8; ++f) {
            O[f][0] *= crr[0];
            O[f][1] *= crr[1];
        }

        // K reads + P writes retired; V(ti) loads (issued post-PV of ti-1) drained.
        asm volatile("s_waitcnt vmcnt(0) lgkmcnt(0)" ::: "memory");
        __builtin_amdgcn_sched_barrier(0);
        __builtin_amdgcn_s_barrier();                    // #1: K free, V(ti) visible
        if (ti + 1 < NT) issue_K(kv_base + (ti + 1) * 64);   // hidden under PV
        __builtin_amdgcn_sched_barrier(0);

        // ---- PV (reads Vb + Pl) ----
        __builtin_amdgcn_s_setprio(1);
#pragma unroll
        for (int ks = 0; ks < 2; ++ks) {
            short8 pb[2];
#pragma unroll
            for (int b = 0; b < 2; ++b) {
                const int row = b * 16 + ll;
                pb[b] = *(const short8*)&Pl[w][row][((ks * 4 + lg) ^ (ll & 7)) * 8];
            }
#pragma unroll
            for (int f = 0; f < 8; ++f) {
                const int row = f * 16 + ll;
                short8 va = *(const short8*)&Vb[row * 64
                                               + (((ks * 4 + lg) ^ (ll & 7)) * 8)];
                O[f][0] = mfma16(va, pb[0], O[f][0]);
                O[f][1] = mfma16(va, pb[1], O[f][1]);
            }
        }
        __builtin_amdgcn_s_setprio(0);

        __builtin_amdgcn_s_barrier();                    // #2: V buffer free
        if (ti + 1 < NT) issue_V(kv_base + (ti + 1) * 64);   // hidden under QK^T(t+1)
        asm volatile("s_waitcnt vmcnt(4)" ::: "memory");     // K(t+1) done, V flying
        __builtin_amdgcn_sched_barrier(0);
        __builtin_amdgcn_s_barrier();                    // #3: K(t+1) visible
    }

    // epilogue: O[f][b][j] holds h = f*16 + 4*lg + j, q = qt*128 + w*32 + b*16 + ll
    const size_t obase = ((((size_t)split * 4 + bb) * 32 + qt) * 4 + w) * 16;
#pragma unroll
    for (int f = 0; f < 8; ++f)
#pragma unroll
        for (int b = 0; b < 2; ++b)
            *(float4v*)&Opart[(obase + f * 2 + b) * 256 + l * 4] = O[f][b];

    if (lg == 0) {
#pragma unroll
        for (int b = 0; b < 2; ++b) {
            const int q = qt * 128 + w * 32 + b * 16 + ll;
            msb[((size_t)split * 4 + bb) * LQ + q] = mold[b];
            lsb[((size_t)split * 4 + bb) * LQ + q] = lsum[b];
        }
    }

    // ---- fused combine: last split-block of this (bb,qt) group reduces ----
    __syncthreads();                 // all partial stores issued
    __threadfence();                 // release: partials device-visible
    if (t == 0) {
        unsigned int old = atomicAdd(&cnt[(bb << 5) + qt], 1u);
        sflag = (old == 3u) ? 1u : 0u;
    }
    __syncthreads();
    if (sflag) {
        __threadfence();             // acquire: invalidate stale caches
#pragma unroll
        for (int b = 0; b < 2; ++b) {
            const int q = qt * 128 + w * 32 + b * 16 + ll;
            float ms[NSPLIT], ls[NSPLIT];
#pragma unroll
            for (int s = 0; s < NSPLIT; ++s) {
                ms[s] = msb[((size_t)s * 4 + bb) * LQ + q];
                ls[s] = lsb[((size_t)s * 4 + bb) * LQ + q];
            }
            float mM = fmaxf(fmaxf(ms[0], ms[1]), fmaxf(ms[2], ms[3]));
            float wsp[NSPLIT];
            float L = 0.f;
#pragma unroll
            for (int s = 0; s < NSPLIT; ++s) {
                wsp[s] = exp2f(ms[s] - mM);
                L += ls[s] * wsp[s];
            }
            const float inv = 1.f / L;
#pragma unroll
            for (int f = 0; f < 8; ++f) {
                f32x4 acc = {0.f, 0.f, 0.f, 0.f};
#pragma unroll
                for (int s = 0; s < NSPLIT; ++s) {
                    const size_t ob = ((((size_t)s * 4 + bb) * 32 + qt) * 4 + w) * 16
                                    + f * 2 + b;
                    float4v ov = *(const float4v*)&Opart[ob * 256 + l * 4];
#pragma unroll
                    for (int j = 0; j < 4; ++j) acc[j] += ov[j] * wsp[s];
                }
#pragma unroll
                for (int j = 0; j < 4; ++j) acc[j] *= inv;
                *(float4v*)&out[((size_t)bb * LQ + q) * H_ + f * 16 + lg * 4] = acc;
            }
        }
    }
}

extern "C" void kernel_launch(void* const* d_in, const int* in_sizes, int n_in,
                              void* d_out, int out_size, void* d_ws, size_t ws_size,
                              hipStream_t stream) {
    const float* x  = (const float*)d_in[0];
    const float* z  = (const float*)d_in[1];
    const float* Wq = (const float*)d_in[2];
    const float* Wk = (const float*)d_in[3];
    const float* Wv = (const float*)d_in[4];
    float* out = (float*)d_out;

    const size_t NQ = (size_t)B_ * LQ * H_;   // 2,097,152
    unsigned short* qhi = (unsigned short*)d_ws;
    unsigned short* qlo = qhi + NQ;
    unsigned short* khi = qlo + NQ;
    unsigned short* klo = khi + NQ;
    unsigned short* vtp = klo + NQ;           // 5 * 4 MiB = 20 MiB
    float* Opart = (float*)(vtp + NQ);        // NSPLIT * NQ f32 = 32 MiB
    float* msb   = Opart + (size_t)NSPLIT * NQ;
    float* lsb   = msb + (size_t)NSPLIT * B_ * LQ;
    unsigned short* wqh = (unsigned short*)(lsb + (size_t)NSPLIT * B_ * LQ);
    unsigned short* wql = wqh + WELEM;
    unsigned short* wkh = wql + WELEM;
    unsigned short* wkl = wkh + WELEM;
    unsigned short* wvh = wkl + WELEM;        // +1.25 MiB
    unsigned int* cnt = (unsigned int*)(wvh + WELEM);   // 128 counters (512 B)

    convert_w_kernel<<<dim3(16, 3), 256, 0, stream>>>(Wq, Wk, Wv, wqh, wql, wkh,
                                                      wkl, wvh, cnt);
    proj_kernel<<<dim3(256), 512, 0, stream>>>(x, z, wqh, wql, wkh, wkl, wvh,
                                               qhi, qlo, khi, klo, vtp);
    attn_kernel<<<dim3(512), 256, 0, stream>>>(qhi, qlo, khi, klo, vtp,
                                               Opart, msb, lsb, out, cnt);
}

// Round 12
// 135.230 us; speedup vs baseline: 1.4680x; 1.4680x over previous
//
#include <hip/hip_runtime.h>

typedef __attribute__((ext_vector_type(8))) short short8;
typedef __attribute__((ext_vector_type(4))) float f32x4;
typedef __attribute__((ext_vector_type(4))) float float4v;
typedef __attribute__((ext_vector_type(4))) unsigned short ushort4v;
typedef unsigned int __attribute__((may_alias)) u32ma;

#define B_   4
#define LQ   4096
#define LKV  4096
#define E_   1024
#define H_   128
#define NSPLIT 4
#define KVSPL (LKV / NSPLIT)   // 1024
#define NT    (KVSPL / 64)     // 16
#define WELEM (H_ * E_)        // 131072 elements per weight matrix

static __device__ __forceinline__ unsigned short bf16_rne(float f) {
    unsigned int u = __float_as_uint(f);
    u += 0x7fffu + ((u >> 16) & 1u);
    return (unsigned short)(u >> 16);
}
static __device__ __forceinline__ float bf16_tof(unsigned short h) {
    return __uint_as_float(((unsigned int)h) << 16);
}
static __device__ __forceinline__ f32x4 mfma16(short8 a, short8 b, f32x4 c) {
    return __builtin_amdgcn_mfma_f32_16x16x32_bf16(a, b, c, 0, 0, 0);
}
static __device__ __forceinline__ void gload16(const unsigned short* g, unsigned short* l) {
    __builtin_amdgcn_global_load_lds(
        (const __attribute__((address_space(1))) unsigned int*)g,
        (__attribute__((address_space(3))) unsigned int*)l, 16, 0, 0);
}

// ---------------------------------------------------------------------------
// One-time W conversion: f32 -> split bf16 (hi+lo for Wq/Wk, hi for Wv),
// stored PRE-SWIZZLED so proj can global_load_lds linearly.
// ---------------------------------------------------------------------------
__global__ __launch_bounds__(256) void convert_w_kernel(
    const float* __restrict__ Wq, const float* __restrict__ Wk, const float* __restrict__ Wv,
    unsigned short* __restrict__ wqh, unsigned short* __restrict__ wql,
    unsigned short* __restrict__ wkh, unsigned short* __restrict__ wkl,
    unsigned short* __restrict__ wvh)
{
    const int kb = blockIdx.x;       // 0..15
    const int which = blockIdx.y;    // 0:Wq 1:Wk 2:Wv
    const float* W = (which == 0) ? Wq : (which == 1) ? Wk : Wv;
    unsigned short* outh = (which == 0) ? wqh : (which == 1) ? wkh : wvh;
    unsigned short* outl = (which == 0) ? wql : wkl;
    const int t = threadIdx.x;
#pragma unroll
    for (int i = 0; i < 4; ++i) {
        const int c = t * 4 + i;                 // chunk 0..1023
        const int h = c >> 3;
        const int k = kb * 64 + (((c & 7) ^ (h & 7)) * 8);
        const float* src = W + (size_t)h * E_ + k;
        float4v v0 = *(const float4v*)(src);
        float4v v1 = *(const float4v*)(src + 4);
        short8 hi, lo;
#pragma unroll
        for (int e = 0; e < 4; ++e) {
            unsigned short h0 = bf16_rne(v0[e]);
            unsigned short h1 = bf16_rne(v1[e]);
            hi[e] = (short)h0; hi[e + 4] = (short)h1;
            lo[e] = (short)bf16_rne(v0[e] - bf16_tof(h0));
            lo[e + 4] = (short)bf16_rne(v1[e] - bf16_tof(h1));
        }
        *(short8*)&outh[(size_t)kb * 8192 + (size_t)c * 8] = hi;
        if (which < 2) *(short8*)&outl[(size_t)kb * 8192 + (size_t)c * 8] = lo;
    }
}

// ---------------------------------------------------------------------------
// Projection GEMM R7 (verified best): A-tile double-buffered in LDS -> ONE
// barrier per kb. A global loads issued at kb-top (flight ~= full compute);
// W hi/lo double-buffered via global_load_lds; Wv single-buffered, staged in
// the kb tail (W buffers are L2-resident ~200cy, so tail-issue is cheap —
// R8 showed top-issue+dbuf ADDS LDS-write contention and regresses).
// LDS: Ah[2]+Al[2] 64K + Wh[2]+Wl[2] 64K + Wv2 16K = 144 KiB (1 block/CU).
// ---------------------------------------------------------------------------
__global__ __launch_bounds__(512, 1) void proj_kernel(
    const float* __restrict__ x, const float* __restrict__ z,
    const unsigned short* __restrict__ wqh, const unsigned short* __restrict__ wql,
    const unsigned short* __restrict__ wkh, const unsigned short* __restrict__ wkl,
    const unsigned short* __restrict__ wvh,
    unsigned short* __restrict__ qhi, unsigned short* __restrict__ qlo,
    unsigned short* __restrict__ khi, unsigned short* __restrict__ klo,
    unsigned short* __restrict__ vt)
{
    const int bid = blockIdx.x;
    const bool qmode = bid < 128;
    const int m0 = (qmode ? bid : bid - 128) * 128;
    const float* Asrc = qmode ? x : z;
    const unsigned short* W1h = qmode ? wqh : wkh;
    const unsigned short* W1l = qmode ? wql : wkl;

    const int t = threadIdx.x;
    const int w = t >> 6, l = t & 63, lg = (l >> 4) & 3, ll = l & 15;
    const int mw = w & 3, nw = w >> 2;

    __shared__ unsigned short Ah[2][8192];     // 32 KiB [128 r][64 k] swizzled, dbuf
    __shared__ unsigned short Al[2][8192];     // 32 KiB
    __shared__ unsigned short Wh[2][8192];     // 32 KiB [128 h][64 k] swizzled, dbuf
    __shared__ unsigned short Wl[2][8192];     // 32 KiB
    __shared__ unsigned short Wv2[8192];       // 16 KiB single (kv-mode only)

    const int ar = t >> 2, aq = t & 3;
    float4v ra[4];
    auto loadA = [&](int e0) {
        const float* p = Asrc + (size_t)(m0 + ar) * E_ + e0 + aq * 16;
#pragma unroll
        for (int i = 0; i < 4; ++i) ra[i] = *(const float4v*)(p + i * 4);
    };
    auto writeA = [&](int ab) {
#pragma unroll
        for (int half = 0; half < 2; ++half) {
            short8 hi, lo;
#pragma unroll
            for (int e = 0; e < 4; ++e) {
                float v0 = ra[2 * half][e];
                float v1 = ra[2 * half + 1][e];
                unsigned short h0 = bf16_rne(v0);
                unsigned short h1 = bf16_rne(v1);
                hi[e] = (short)h0; hi[e + 4] = (short)h1;
                lo[e] = (short)bf16_rne(v0 - bf16_tof(h0));
                lo[e + 4] = (short)bf16_rne(v1 - bf16_tof(h1));
            }
            const int j = 2 * aq + half;
            const int off = ar * 64 + ((j ^ (ar & 7)) * 8);
            *(short8*)&Ah[ab][off] = hi;
            *(short8*)&Al[ab][off] = lo;
        }
    };
    auto issueW = [&](int kb, int bsel) {      // Wh+Wl only: 4 gloads/wave
#pragma unroll
        for (int i = 0; i < 2; ++i) {
            const int cbase = w * 128 + i * 64;
            const size_t so = (size_t)kb * 8192 + (size_t)(cbase + l) * 8;
            gload16(W1h + so, &Wh[bsel][(size_t)cbase * 8]);
            gload16(W1l + so, &Wl[bsel][(size_t)cbase * 8]);
        }
    };
    auto issueWv = [&](int kb) {               // 2 gloads/wave
#pragma unroll
        for (int i = 0; i < 2; ++i) {
            const int cbase = w * 128 + i * 64;
            const size_t so = (size_t)kb * 8192 + (size_t)(cbase + l) * 8;
            gload16(wvh + so, &Wv2[(size_t)cbase * 8]);
        }
    };

    f32x4 acc[2][4], accv[2][4];
    const f32x4 zz = {0.f, 0.f, 0.f, 0.f};
#pragma unroll
    for (int rf = 0; rf < 2; ++rf)
#pragma unroll
        for (int cf = 0; cf < 4; ++cf) { acc[rf][cf] = zz; accv[rf][cf] = zz; }

    loadA(0);
    issueW(0, 0);
    if (!qmode) issueWv(0);
    asm volatile("s_waitcnt vmcnt(0)" ::: "memory");
    writeA(0);
    asm volatile("s_waitcnt lgkmcnt(0)" ::: "memory");
    __builtin_amdgcn_s_barrier();

    for (int kb = 0; kb < 16; ++kb) {
        const int cur = kb & 1;
        if (kb < 15) {
            loadA((kb + 1) * 64);          // A(kb+1) -> ra (flight = full compute)
            issueW(kb + 1, cur ^ 1);       // W(kb+1) -> spare buffer
        }

#pragma unroll
        for (int ks = 0; ks < 2; ++ks) {
            short8 a_h[2], a_l[2];
#pragma unroll
            for (int rf = 0; rf < 2; ++rf) {
                const int r = mw * 32 + rf * 16 + ll;
                const int off = r * 64 + (((ks * 4 + lg) ^ (ll & 7)) * 8);
                a_h[rf] = *(const short8*)&Ah[cur][off];
                a_l[rf] = *(const short8*)&Al[cur][off];
            }
#pragma unroll
            for (int cf = 0; cf < 4; ++cf) {
                const int hrow = nw * 64 + cf * 16 + ll;
                const int off = hrow * 64 + (((ks * 4 + lg) ^ (ll & 7)) * 8);
                short8 bh = *(const short8*)&Wh[cur][off];
                short8 bl = *(const short8*)&Wl[cur][off];
#pragma unroll
                for (int rf = 0; rf < 2; ++rf) {
                    acc[rf][cf] = mfma16(a_h[rf], bh, acc[rf][cf]);
                    acc[rf][cf] = mfma16(a_h[rf], bl, acc[rf][cf]);
                    acc[rf][cf] = mfma16(a_l[rf], bh, acc[rf][cf]);
                }
                if (!qmode) {
                    short8 bv = *(const short8*)&Wv2[off];
#pragma unroll
                    for (int rf = 0; rf < 2; ++rf)
                        accv[rf][cf] = mfma16(a_h[rf], bv, accv[rf][cf]);
                }
            }
        }

        if (kb < 15) {
            writeA(cur ^ 1);               // A(kb+1) -> spare (compiler waits ra)
            if (!qmode) issueWv(kb + 1);   // Wv(kb+1) -> single buf (L2-hit, cheap)
            asm volatile("s_waitcnt vmcnt(0) lgkmcnt(0)" ::: "memory");
            __builtin_amdgcn_sched_barrier(0);
            __builtin_amdgcn_s_barrier();  // ONE barrier per kb
        }
    }

    // epilogue: D layout col(ll)=W-row h, row(4lg+j)=A-row m  [verified R1-R3]
#pragma unroll
    for (int rf = 0; rf < 2; ++rf)
#pragma unroll
        for (int cf = 0; cf < 4; ++cf)
#pragma unroll
            for (int j = 0; j < 4; ++j) {
                const int m = m0 + mw * 32 + rf * 16 + 4 * lg + j;
                const int h = nw * 64 + cf * 16 + ll;
                const float val = acc[rf][cf][j];
                unsigned short hi = bf16_rne(val);
                unsigned short lo = bf16_rne(val - bf16_tof(hi));
                const size_t o = (size_t)m * H_ + h;
                if (qmode) {
                    qhi[o] = hi; qlo[o] = lo;
                } else {
                    khi[o] = hi; klo[o] = lo;
                    const int b = m >> 12, kv = m & 4095;
                    vt[(size_t)b * ((size_t)H_ * LKV) + (size_t)h * LKV + kv] =
                        bf16_rne(accv[rf][cf][j]);
                }
            }
}

// ---------------------------------------------------------------------------
// Flash attention (R3 verbatim — verified best: 84.5 us). 4-wave blocks,
// 32 q-rows/wave, 64 KiB LDS -> 2 independent blocks/CU. 3-barrier schedule.
// Opart stays F32 (R11 lesson: unnormalized split partials reach ~500 in
// magnitude on flat-softmax rows — bf16 partials blow the tolerance).
// ---------------------------------------------------------------------------
__global__ __launch_bounds__(256, 2) void attn_kernel(
    const unsigned short* __restrict__ qhi, const unsigned short* __restrict__ qlo,
    const unsigned short* __restrict__ khi, const unsigned short* __restrict__ klo,
    const unsigned short* __restrict__ vt,
    float* __restrict__ Opart, float* __restrict__ msb, float* __restrict__ lsb)
{
    const int blk = blockIdx.x;         // 512 blocks
    const int bb = blk & 3;
    const int qt = (blk >> 2) & 31;
    const int split = blk >> 7;
    const int t = threadIdx.x;          // 0..255
    const int w = t >> 6, l = t & 63, lg = (l >> 4) & 3, ll = l & 15;

    __shared__ unsigned short Kh[8192];        // 16 KiB [64 kv][128 h] swizzled
    __shared__ unsigned short Kl[8192];        // 16 KiB
    __shared__ unsigned short Vb[8192];        // 16 KiB [128 h][64 kv] swizzled
    __shared__ unsigned short Pl[4][32][64];   // 16 KiB per-wave P staging

    const float CSC = 11.313708498984761f * 1.4426950408889634f;

    short8 qh[2][4], ql[2][4];
#pragma unroll
    for (int b = 0; b < 2; ++b) {
        const size_t qrow = (size_t)(bb * LQ + qt * 128 + w * 32 + b * 16 + ll) * H_;
#pragma unroll
        for (int ks = 0; ks < 4; ++ks) {
            qh[b][ks] = *(const short8*)(qhi + qrow + ks * 32 + lg * 8);
            ql[b][ks] = *(const short8*)(qlo + qrow + ks * 32 + lg * 8);
        }
    }

    const int kv_base = split * KVSPL;
    const unsigned short* khb = khi + (size_t)bb * LKV * H_;
    const unsigned short* klb = klo + (size_t)bb * LKV * H_;
    const unsigned short* vbg = vt + (size_t)bb * ((size_t)H_ * LKV);

    auto issue_K = [&](int kv0) {     // 8 loads/wave
#pragma unroll
        for (int ci = 0; ci < 4; ++ci) {
            const int chunk = w * 4 + ci;              // 0..15
            const int row = chunk * 4 + (l >> 4);      // kv row 0..63
            const int c = l & 15;                      // col-chunk
            const size_t so = (size_t)(kv0 + row) * H_ + ((c ^ (row & 7)) * 8);
            gload16(khb + so, &Kh[chunk * 512]);
            gload16(klb + so, &Kl[chunk * 512]);
        }
    };
    auto issue_V = [&](int kv0) {     // 4 loads/wave
#pragma unroll
        for (int ci = 0; ci < 4; ++ci) {
            const int chunk = w * 4 + ci;              // 0..15
            const int row = chunk * 8 + (l >> 3);      // h row 0..127
            const int c = l & 7;                       // col-chunk
            gload16(vbg + (size_t)row * LKV + kv0 + ((c ^ (row & 7)) * 8),
                    &Vb[chunk * 512]);
        }
    };

    f32x4 O[8][2];
    const f32x4 zz = {0.f, 0.f, 0.f, 0.f};
#pragma unroll
    for (int f = 0; f < 8; ++f) { O[f][0] = zz; O[f][1] = zz; }
    float mold[2] = {-1e30f, -1e30f};
    float lsum[2] = {0.f, 0.f};

    issue_K(kv_base);
    issue_V(kv_base);
    asm volatile("s_waitcnt vmcnt(0)" ::: "memory");
    __builtin_amdgcn_s_barrier();

    for (int ti = 0; ti < NT; ++ti) {
        // ---- QK^T (reads Kh/Kl; K(ti) drained at barrier#3 of ti-1) ----
        f32x4 S[4][2];
#pragma unroll
        for (int a = 0; a < 4; ++a) { S[a][0] = zz; S[a][1] = zz; }
        __builtin_amdgcn_s_setprio(1);
#pragma unroll
        for (int ks = 0; ks < 4; ++ks) {
#pragma unroll
            for (int a = 0; a < 4; ++a) {
                const int row = a * 16 + ll;
                const int off = row * 128 + (((ks * 4 + lg) ^ (ll & 7)) * 8);
                short8 kh  = *(const short8*)&Kh[off];
                short8 kl2 = *(const short8*)&Kl[off];
                S[a][0] = mfma16(kh,  qh[0][ks], S[a][0]);
                S[a][0] = mfma16(kh,  ql[0][ks], S[a][0]);
                S[a][0] = mfma16(kl2, qh[0][ks], S[a][0]);
                S[a][1] = mfma16(kh,  qh[1][ks], S[a][1]);
                S[a][1] = mfma16(kh,  ql[1][ks], S[a][1]);
                S[a][1] = mfma16(kl2, qh[1][ks], S[a][1]);
            }
        }
        __builtin_amdgcn_s_setprio(0);

        // ---- online softmax (per-wave; writes Pl[w]) ----
        float crr[2];
#pragma unroll
        for (int b = 0; b < 2; ++b) {
            float mx = S[0][b][0];
#pragma unroll
            for (int a = 0; a < 4; ++a)
#pragma unroll
                for (int j = 0; j < 4; ++j) mx = fmaxf(mx, S[a][b][j]);
            mx = fmaxf(mx, __shfl_xor(mx, 16));
            mx = fmaxf(mx, __shfl_xor(mx, 32));
            float mn = fmaxf(mold[b], mx * CSC);
            float corr = exp2f(mold[b] - mn);
            float ps = 0.f;
#pragma unroll
            for (int a = 0; a < 4; ++a) {
                float p0 = exp2f(fmaf(S[a][b][0], CSC, -mn));
                float p1 = exp2f(fmaf(S[a][b][1], CSC, -mn));
                float p2 = exp2f(fmaf(S[a][b][2], CSC, -mn));
                float p3 = exp2f(fmaf(S[a][b][3], CSC, -mn));
                ps += (p0 + p1) + (p2 + p3);
                unsigned int pk0, pk1;
                asm("v_cvt_pk_bf16_f32 %0, %1, %2" : "=v"(pk0) : "v"(p0), "v"(p1));
                asm("v_cvt_pk_bf16_f32 %0, %1, %2" : "=v"(pk1) : "v"(p2), "v"(p3));
                const int row = b * 16 + ll;
                u32ma* pd = (u32ma*)&Pl[w][0][0];
                const int di = row * 32 + (((2 * a + (lg >> 1)) ^ (ll & 7)) * 4) + 2 * (lg & 1);
                pd[di] = pk0;
                pd[di + 1] = pk1;
            }
            ps += __shfl_xor(ps, 16);
            ps += __shfl_xor(ps, 32);
            lsum[b] = lsum[b] * corr + ps;
            mold[b] = mn;
            crr[b] = corr;
        }
#pragma unroll
        for (int f = 0; f < 8; ++f) {
            O[f][0] *= crr[0];
            O[f][1] *= crr[1];
        }

        // K reads + P writes retired; V(ti) loads (issued post-PV of ti-1) drained.
        asm volatile("s_waitcnt vmcnt(0) lgkmcnt(0)" ::: "memory");
        __builtin_amdgcn_sched_barrier(0);
        __builtin_amdgcn_s_barrier();                    // #1: K free, V(ti) visible
        if (ti + 1 < NT) issue_K(kv_base + (ti + 1) * 64);   // hidden under PV
        __builtin_amdgcn_sched_barrier(0);

        // ---- PV (reads Vb + Pl) ----
        __builtin_amdgcn_s_setprio(1);
#pragma unroll
        for (int ks = 0; ks < 2; ++ks) {
            short8 pb[2];
#pragma unroll
            for (int b = 0; b < 2; ++b) {
                const int row = b * 16 + ll;
                pb[b] = *(const short8*)&Pl[w][row][((ks * 4 + lg) ^ (ll & 7)) * 8];
            }
#pragma unroll
            for (int f = 0; f < 8; ++f) {
                const int row = f * 16 + ll;
                short8 va = *(const short8*)&Vb[row * 64
                                               + (((ks * 4 + lg) ^ (ll & 7)) * 8)];
                O[f][0] = mfma16(va, pb[0], O[f][0]);
                O[f][1] = mfma16(va, pb[1], O[f][1]);
            }
        }
        __builtin_amdgcn_s_setprio(0);

        __builtin_amdgcn_s_barrier();                    // #2: V buffer free
        if (ti + 1 < NT) issue_V(kv_base + (ti + 1) * 64);   // hidden under QK^T(t+1)
        asm volatile("s_waitcnt vmcnt(4)" ::: "memory");     // K(t+1) done, V flying
        __builtin_amdgcn_sched_barrier(0);
        __builtin_amdgcn_s_barrier();                    // #3: K(t+1) visible
    }

    // epilogue: O[f][b][j] holds h = f*16 + 4*lg + j, q = qt*128 + w*32 + b*16 + ll
    const size_t obase = ((((size_t)split * 4 + bb) * 32 + qt) * 4 + w) * 16;
#pragma unroll
    for (int f = 0; f < 8; ++f)
#pragma unroll
        for (int b = 0; b < 2; ++b)
            *(float4v*)&Opart[(obase + f * 2 + b) * 256 + l * 4] = O[f][b];

    if (lg == 0) {
#pragma unroll
        for (int b = 0; b < 2; ++b) {
            const int q = qt * 128 + w * 32 + b * 16 + ll;
            msb[((size_t)split * 4 + bb) * LQ + q] = mold[b];
            lsb[((size_t)split * 4 + bb) * LQ + q] = lsum[b];
        }
    }
}

// ---------------------------------------------------------------------------
// Combine the 4 KV-split partials (R3 verbatim, f32 Opart).
// ---------------------------------------------------------------------------
__global__ __launch_bounds__(512) void combine_kernel(
    const float* __restrict__ Opart, const float* __restrict__ msb,
    const float* __restrict__ lsb, float* __restrict__ out)
{
    const int blk = blockIdx.x;
    const int bb = blk & 3;
    const int qt = (blk >> 2) & 31;
    const int fg = blk >> 7;             // 0..1
    const int t = threadIdx.x;
    const int w = t >> 6, l = t & 63, lg = (l >> 4) & 3, ll = l & 15;
    const int wq = w & 3, wf = w >> 2;

#pragma unroll
    for (int b = 0; b < 2; ++b) {
        const int q = qt * 128 + wq * 32 + b * 16 + ll;
        float ms[NSPLIT], ls[NSPLIT];
#pragma unroll
        for (int s = 0; s < NSPLIT; ++s) {
            ms[s] = msb[((size_t)s * 4 + bb) * LQ + q];
            ls[s] = lsb[((size_t)s * 4 + bb) * LQ + q];
        }
        float mM = fmaxf(fmaxf(ms[0], ms[1]), fmaxf(ms[2], ms[3]));
        float wsp[NSPLIT];
        float L = 0.f;
#pragma unroll
        for (int s = 0; s < NSPLIT; ++s) {
            wsp[s] = exp2f(ms[s] - mM);
            L += ls[s] * wsp[s];
        }
        const float inv = 1.f / L;
#pragma unroll
        for (int fi = 0; fi < 2; ++fi) {
            const int f = fg * 4 + wf * 2 + fi;
            f32x4 acc = {0.f, 0.f, 0.f, 0.f};
#pragma unroll
            for (int s = 0; s < NSPLIT; ++s) {
                const size_t ob = ((((size_t)s * 4 + bb) * 32 + qt) * 4 + wq) * 16 + f * 2 + b;
                float4v ov = *(const float4v*)&Opart[ob * 256 + l * 4];
#pragma unroll
                for (int j = 0; j < 4; ++j) acc[j] += ov[j] * wsp[s];
            }
#pragma unroll
            for (int j = 0; j < 4; ++j) acc[j] *= inv;
            *(float4v*)&out[((size_t)bb * LQ + q) * H_ + f * 16 + lg * 4] = acc;
        }
    }
}

extern "C" void kernel_launch(void* const* d_in, const int* in_sizes, int n_in,
                              void* d_out, int out_size, void* d_ws, size_t ws_size,
                              hipStream_t stream) {
    const float* x  = (const float*)d_in[0];
    const float* z  = (const float*)d_in[1];
    const float* Wq = (const float*)d_in[2];
    const float* Wk = (const float*)d_in[3];
    const float* Wv = (const float*)d_in[4];
    float* out = (float*)d_out;

    const size_t NQ = (size_t)B_ * LQ * H_;   // 2,097,152
    unsigned short* qhi = (unsigned short*)d_ws;
    unsigned short* qlo = qhi + NQ;
    unsigned short* khi = qlo + NQ;
    unsigned short* klo = khi + NQ;
    unsigned short* vtp = klo + NQ;           // 5 * 4 MiB = 20 MiB
    float* Opart = (float*)(vtp + NQ);        // NSPLIT * NQ f32 = 32 MiB
    float* msb   = Opart + (size_t)NSPLIT * NQ;
    float* lsb   = msb + (size_t)NSPLIT * B_ * LQ;
    unsigned short* wqh = (unsigned short*)(lsb + (size_t)NSPLIT * B_ * LQ);
    unsigned short* wql = wqh + WELEM;
    unsigned short* wkh = wql + WELEM;
    unsigned short* wkl = wkh + WELEM;
    unsigned short* wvh = wkl + WELEM;        // +1.25 MiB

    convert_w_kernel<<<dim3(16, 3), 256, 0, stream>>>(Wq, Wk, Wv, wqh, wql, wkh, wkl, wvh);
    proj_kernel<<<dim3(256), 512, 0, stream>>>(x, z, wqh, wql, wkh, wkl, wvh,
                                               qhi, qlo, khi, klo, vtp);
    attn_kernel<<<dim3(512), 256, 0, stream>>>(qhi, qlo, khi, klo, vtp, Opart, msb, lsb);
    combine_kernel<<<dim3(256), 512, 0, stream>>>(Opart, msb, lsb, out);
}